// Round 1
// baseline (103.680 us; speedup 1.0000x reference)
//
#include <hip/hip_runtime.h>

// Problem constants (match reference)
#define NDIM    128
#define NVOCAB  100000
#define BATCH   16384
#define NS      10
#define NCTX    4                      // WINDOW-1 context words
#define NDOT    (NCTX + NCTX * NS)     // 44 dot products per batch element
#define TOTAL   (BATCH * NDOT)         // 720896 threads

// stable log(sigmoid(x)) = min(x,0) - log1p(exp(-|x|)); never -inf
__device__ __forceinline__ float logsigmoidf(float x) {
    return fminf(x, 0.0f) - log1pf(expf(-fabsf(x)));
}

__global__ __launch_bounds__(256) void w2v_loss_kernel(
    const int* __restrict__ input_ids,   // [5, BATCH]
    const int* __restrict__ nsi,         // [4, BATCH, NS]
    const float* __restrict__ W,         // [NVOCAB, NDIM]
    double* __restrict__ sums)           // sums[0] = sum_l, sums[1] = sum_r
{
    const int tid = threadIdx.x;
    const int idx = blockIdx.x * blockDim.x + tid;

    float lc = 0.0f;   // positive-term contribution
    float rc = 0.0f;   // negative-term contribution

    if (idx < TOTAL) {
        const int b = idx / NDOT;
        const int r = idx - b * NDOT;

        // center word embedding row
        const int ci = input_ids[2 * BATCH + b];

        int  ri;
        bool pos;
        if (r < NCTX) {
            pos = true;
            const int w = r + (r >= 2 ? 1 : 0);   // skip center row: {0,1,3,4}
            ri = input_ids[w * BATCH + b];
        } else {
            pos = false;
            const int j = r - NCTX;               // 0..39
            const int w = j / NS;                 // 0..3
            const int n = j - w * NS;             // 0..9
            ri = nsi[(w * BATCH + b) * NS + n];
        }

        const float4* __restrict__ vi = (const float4*)(W + (size_t)ci * NDIM);
        const float4* __restrict__ vr = (const float4*)(W + (size_t)ri * NDIM);

        float acc = 0.0f;
        #pragma unroll
        for (int d = 0; d < NDIM / 4; ++d) {
            const float4 a = vi[d];
            const float4 x = vr[d];
            acc += a.x * x.x + a.y * x.y + a.z * x.z + a.w * x.w;
        }

        if (pos) {
            lc = logsigmoidf(acc);                // log(sigmoid(vo.vi))
        } else {
            // reference: s = sigmoid(-acc); s==0 -> 1e-9; log(s)
            if (acc > 88.7f) {
                rc = -20.723265837f;              // log(1e-9), emulate fp32 underflow clamp
            } else {
                rc = logsigmoidf(-acc);
            }
        }
    }

    // block reduction of the two partial sums
    __shared__ float sl[256];
    __shared__ float sr[256];
    sl[tid] = lc;
    sr[tid] = rc;
    __syncthreads();
    #pragma unroll
    for (int o = 128; o > 0; o >>= 1) {
        if (tid < o) {
            sl[tid] += sl[tid + o];
            sr[tid] += sr[tid + o];
        }
        __syncthreads();
    }
    if (tid == 0) {
        atomicAdd(&sums[0], (double)sl[0]);
        atomicAdd(&sums[1], (double)sr[0]);
    }
}

__global__ void w2v_finalize_kernel(const double* __restrict__ sums,
                                    float* __restrict__ out)
{
    const double mean_l = sums[0] / (double)(BATCH * NCTX);
    const double mean_r = sums[1] / (double)(BATCH * NCTX * NS);
    out[0] = (float)(-(mean_l + mean_r));
}

extern "C" void kernel_launch(void* const* d_in, const int* in_sizes, int n_in,
                              void* d_out, int out_size, void* d_ws, size_t ws_size,
                              hipStream_t stream)
{
    const int*   input_ids = (const int*)d_in[0];   // [5, BATCH]
    const int*   nsi       = (const int*)d_in[1];   // [4, BATCH, NS]
    const float* W         = (const float*)d_in[2]; // [NVOCAB, NDIM]
    float*       out       = (float*)d_out;
    double*      sums      = (double*)d_ws;

    hipMemsetAsync(d_ws, 0, 2 * sizeof(double), stream);

    const int blocks = (TOTAL + 255) / 256;         // 2816
    w2v_loss_kernel<<<blocks, 256, 0, stream>>>(input_ids, nsi, W, sums);
    w2v_finalize_kernel<<<1, 1, 0, stream>>>(sums, out);
}